// Round 1
// baseline (2585.454 us; speedup 1.0000x reference)
//
#include <hip/hip_runtime.h>
#include <hip/hip_bf16.h>
#include <math.h>

// Problem constants (fixed by reference: B=8, C=128, N=1024, UP=4)
#define BB    8
#define CC    128
#define NN    1024
#define MM    4096     // UP*N
#define CIN   130      // C+2
#define CQ    32       // Cin//4
#define NROWS 194      // 32 (f) + 32 (g) + 130 (h) stacked

// fgh buffer rows: [0,32) = f, [32,64) = g, [64,194) = h, each [row][M] per batch.

// ---------------------------------------------------------------------------
// K1: fgh = relu(W @ net + b) for all three projections, fused net construction.
// net[b,c,m] = inputs[b,c,m%N] for c<128; grid-x (c=128), grid-y (c=129).
// grid rows (m>>10): (-.2,-.2), (-.2,.2), (.2,-.2), (.2,.2)
// ---------------------------------------------------------------------------
__global__ __launch_bounds__(256) void fgh_kernel(
    const float* __restrict__ inp,
    const float* __restrict__ WF, const float* __restrict__ bF,
    const float* __restrict__ WG, const float* __restrict__ bG,
    const float* __restrict__ WH, const float* __restrict__ bH,
    float* __restrict__ fgh)
{
    const int b  = blockIdx.z;
    const int og = blockIdx.y;                 // 8 output rows per block
    const int m  = blockIdx.x * 256 + threadIdx.x;

    __shared__ float wl[8][CIN];
    __shared__ float bl[8];

    for (int idx = threadIdx.x; idx < 8 * CIN; idx += 256) {
        int i = idx / CIN, c = idx - i * CIN;
        int o = og * 8 + i;
        float w = 0.f;
        if (o < 32)            w = WF[o * CIN + c];
        else if (o < 64)       w = WG[(o - 32) * CIN + c];
        else if (o < NROWS)    w = WH[(o - 64) * CIN + c];
        wl[i][c] = w;
    }
    if (threadIdx.x < 8) {
        int o = og * 8 + threadIdx.x;
        float bv = 0.f;
        if (o < 32)            bv = bF[o];
        else if (o < 64)       bv = bG[o - 32];
        else if (o < NROWS)    bv = bH[o - 64];
        bl[threadIdx.x] = bv;
    }
    __syncthreads();

    float acc[8];
    #pragma unroll
    for (int i = 0; i < 8; ++i) acc[i] = bl[i];

    const int mn = m & (NN - 1);
    #pragma unroll 4
    for (int c = 0; c < CC; ++c) {
        float v = inp[((size_t)b * CC + c) * NN + mn];
        #pragma unroll
        for (int i = 0; i < 8; ++i) acc[i] += wl[i][c] * v;
    }
    const int q = m >> 10;
    const float gx = (q >> 1) ? 0.2f : -0.2f;
    const float gy = (q & 1)  ? 0.2f : -0.2f;
    #pragma unroll
    for (int i = 0; i < 8; ++i) acc[i] += wl[i][CC] * gx + wl[i][CC + 1] * gy;

    const int o0 = og * 8;
    #pragma unroll
    for (int i = 0; i < 8; ++i) {
        int o = o0 + i;
        if (o < NROWS)
            fgh[((size_t)b * NROWS + o) * MM + m] = fmaxf(acc[i], 0.f);
    }
}

// ---------------------------------------------------------------------------
// K2: pass A — L[b][k] = max_m s[k,m] + log(sum_m exp(s[k,m]-max))
// with s[k,m] = sum_c g[c,k]*f[c,m] (dot of 32).
// Block: 32 k-rows, 8 threads per row, m streamed in chunks of 64 via LDS.
// ---------------------------------------------------------------------------
__global__ __launch_bounds__(256) void rowstats_kernel(
    const float* __restrict__ fgh, float* __restrict__ L)
{
    const int b  = blockIdx.y;
    const int k0 = blockIdx.x * 32;
    const int tid = threadIdx.x;
    const int kr = tid >> 3, ml = tid & 7;
    const int k  = k0 + kr;

    __shared__ float fl[CQ][64];

    float greg[CQ];
    #pragma unroll
    for (int c = 0; c < CQ; ++c)
        greg[c] = fgh[((size_t)b * NROWS + 32 + c) * MM + k];

    float mx = -1e30f, sm = 0.f;

    for (int mc = 0; mc < MM; mc += 64) {
        __syncthreads();
        for (int idx = tid; idx < CQ * 64; idx += 256) {
            int c = idx >> 6, mm = idx & 63;
            fl[c][mm] = fgh[((size_t)b * NROWS + c) * MM + mc + mm];
        }
        __syncthreads();

        float s[8];
        #pragma unroll
        for (int i = 0; i < 8; ++i) {
            const int mi = ml + 8 * i;
            float a = 0.f;
            #pragma unroll
            for (int c = 0; c < CQ; ++c) a += greg[c] * fl[c][mi];
            s[i] = a;
        }
        float cmx = s[0];
        #pragma unroll
        for (int i = 1; i < 8; ++i) cmx = fmaxf(cmx, s[i]);
        float nmx = fmaxf(mx, cmx);
        float cs = 0.f;
        #pragma unroll
        for (int i = 0; i < 8; ++i) cs += __expf(s[i] - nmx);
        sm = sm * __expf(mx - nmx) + cs;
        mx = nmx;
    }

    // combine the 8 lanes covering this row
    #pragma unroll
    for (int d = 1; d < 8; d <<= 1) {
        float omx = __shfl_xor(mx, d);
        float osm = __shfl_xor(sm, d);
        float nmx = fmaxf(mx, omx);
        sm = sm * __expf(mx - nmx) + osm * __expf(omx - nmx);
        mx = nmx;
    }
    if (ml == 0) L[b * MM + k] = mx + __logf(sm);
}

// ---------------------------------------------------------------------------
// K3: pass B — x[b][c][m] = gamma * sum_k h[c,k]*exp(s[k,m]-L[k]) + net[b,c,m]
// Block owns a 32-wide m-tile (all 130 c). k streamed in chunks of 64.
// e_tile padded to 33 cols: unpadded stride-32 write = 32-way bank conflict.
// ---------------------------------------------------------------------------
__global__ __launch_bounds__(256) void attn_kernel(
    const float* __restrict__ fgh, const float* __restrict__ L,
    const float* __restrict__ inp, const float* __restrict__ gamma_p,
    float* __restrict__ x)
{
    const int b  = blockIdx.y;
    const int m0 = blockIdx.x * 32;
    const int tid = threadIdx.x;

    __shared__ float ftile[CQ][32];      // f columns for this m-tile
    __shared__ float gch[CQ][64];        // g k-chunk
    __shared__ float hch[CIN][64];       // h k-chunk
    __shared__ float ech[64][33];        // exp(s-L) tile, padded
    __shared__ float Lch[64];

    for (int idx = tid; idx < CQ * 32; idx += 256) {
        int c = idx >> 5, mm = idx & 31;
        ftile[c][mm] = fgh[((size_t)b * NROWS + c) * MM + m0 + mm];
    }

    float acc[17];
    #pragma unroll
    for (int j = 0; j < 17; ++j) acc[j] = 0.f;

    const int mi = tid & 31, cg = tid >> 5;   // accumulate-phase mapping
    const int kk = tid & 63, mg = tid >> 6;   // E-phase mapping

    for (int kc = 0; kc < MM; kc += 64) {
        __syncthreads();
        for (int idx = tid; idx < CQ * 64; idx += 256) {
            int c = idx >> 6, k2 = idx & 63;
            gch[c][k2] = fgh[((size_t)b * NROWS + 32 + c) * MM + kc + k2];
        }
        for (int idx = tid; idx < CIN * 64; idx += 256) {
            int c = idx >> 6, k2 = idx & 63;
            hch[c][k2] = fgh[((size_t)b * NROWS + 64 + c) * MM + kc + k2];
        }
        if (tid < 64) Lch[tid] = L[b * MM + kc + tid];
        __syncthreads();

        // E tile: each wave handles 8 m-columns for its 64 k-rows
        #pragma unroll
        for (int j = 0; j < 8; ++j) {
            const int mm = mg * 8 + j;
            float s = 0.f;
            #pragma unroll
            for (int c = 0; c < CQ; ++c) s += gch[c][kk] * ftile[c][mm];
            ech[kk][mm] = __expf(s - Lch[kk]);
        }
        __syncthreads();

        // accumulate O tile: thread = (m, c-group of 17 strided rows)
        for (int k2 = 0; k2 < 64; ++k2) {
            const float e = ech[k2][mi];
            #pragma unroll
            for (int j = 0; j < 16; ++j)
                acc[j] += hch[cg + 8 * j][k2] * e;
            if (cg < 2) acc[16] += hch[cg + 128][k2] * e;
        }
    }

    const float gam = gamma_p[0];
    const int m = m0 + mi;
    const int mn = m & (NN - 1);
    const int q = m >> 10;
    #pragma unroll
    for (int j = 0; j < 17; ++j) {
        const int c = cg + 8 * j;
        if (c < CIN) {
            float nv;
            if (c < CC)      nv = inp[((size_t)b * CC + c) * NN + mn];
            else if (c == CC) nv = (q >> 1) ? 0.2f : -0.2f;
            else              nv = (q & 1) ? 0.2f : -0.2f;
            x[((size_t)b * CIN + c) * MM + m] = gam * acc[j] + nv;
        }
    }
}

// ---------------------------------------------------------------------------
// K4/K5: out = relu(W @ in + b), 1x1 conv. 8 output rows per block, W in LDS.
// ---------------------------------------------------------------------------
template <int CIN_>
__global__ __launch_bounds__(256) void conv_relu_kernel(
    const float* __restrict__ W, const float* __restrict__ bias,
    const float* __restrict__ in, float* __restrict__ out)
{
    const int b  = blockIdx.z;
    const int o0 = blockIdx.y * 8;
    const int m  = blockIdx.x * 256 + threadIdx.x;

    __shared__ float wl[8][CIN_];
    __shared__ float bl[8];

    for (int idx = threadIdx.x; idx < 8 * CIN_; idx += 256) {
        int i = idx / CIN_, c = idx - i * CIN_;
        wl[i][c] = W[(o0 + i) * CIN_ + c];
    }
    if (threadIdx.x < 8) bl[threadIdx.x] = bias[o0 + threadIdx.x];
    __syncthreads();

    float acc[8];
    #pragma unroll
    for (int i = 0; i < 8; ++i) acc[i] = bl[i];

    #pragma unroll 4
    for (int c = 0; c < CIN_; ++c) {
        float v = in[((size_t)b * CIN_ + c) * MM + m];
        #pragma unroll
        for (int i = 0; i < 8; ++i) acc[i] += wl[i][c] * v;
    }

    const int Cout = gridDim.y * 8;
    #pragma unroll
    for (int i = 0; i < 8; ++i)
        out[((size_t)b * Cout + (o0 + i)) * MM + m] = fmaxf(acc[i], 0.f);
}

// ---------------------------------------------------------------------------
extern "C" void kernel_launch(void* const* d_in, const int* in_sizes, int n_in,
                              void* d_out, int out_size, void* d_ws, size_t ws_size,
                              hipStream_t stream)
{
    const float* inp   = (const float*)d_in[0];
    const float* WF    = (const float*)d_in[1];
    const float* bF    = (const float*)d_in[2];
    const float* WG    = (const float*)d_in[3];
    const float* bG    = (const float*)d_in[4];
    const float* WH    = (const float*)d_in[5];
    const float* bH    = (const float*)d_in[6];
    const float* gamma = (const float*)d_in[7];
    const float* W1    = (const float*)d_in[8];
    const float* b1    = (const float*)d_in[9];
    const float* W2    = (const float*)d_in[10];
    const float* b2    = (const float*)d_in[11];
    float* out = (float*)d_out;

    // Workspace layout (floats): fgh | L | x | x1  (~72.6 MiB total)
    float* ws  = (float*)d_ws;
    float* fgh = ws;
    float* L   = fgh + (size_t)BB * NROWS * MM;
    float* x   = L   + (size_t)BB * MM;
    float* x1  = x   + (size_t)BB * CIN * MM;

    fgh_kernel<<<dim3(MM / 256, 25, BB), 256, 0, stream>>>(
        inp, WF, bF, WG, bG, WH, bH, fgh);

    rowstats_kernel<<<dim3(MM / 32, BB), 256, 0, stream>>>(fgh, L);

    attn_kernel<<<dim3(MM / 32, BB), 256, 0, stream>>>(fgh, L, inp, gamma, x);

    conv_relu_kernel<CIN><<<dim3(MM / 256, 32, BB), 256, 0, stream>>>(W1, b1, x, x1);

    conv_relu_kernel<256><<<dim3(MM / 256, 16, BB), 256, 0, stream>>>(W2, b2, x1, out);
}

// Round 2
// 306.950 us; speedup vs baseline: 8.4230x; 8.4230x over previous
//
#include <hip/hip_runtime.h>
#include <hip/hip_bf16.h>
#include <math.h>

// Problem constants (B=8, C=128, N=1024, UP=4)
#define BB    8
#define CC    128
#define NN    1024
#define MM    4096     // UP*N
#define CIN   130      // C+2
#define CQ    32       // Cin//4
#define NROWS 194
#define MPAD  80       // padded LDS row length (bf16 units) for Hs/Et
#define CIN_P 160      // x_t padded channel count (130 -> 160, 5 K-slices)

// ---- Layouts (all bf16 unless noted) -------------------------------------
// f_t  [B][4096][32]   : f transposed, c-fastest  (S B-operand / rowstats B)
// g_t  [B][4096][32]   : g transposed, c-fastest  (S A-operand)
// h    [B][130][4096]  : row-major                (O A-operand, LDS-staged)
// L    [B][4096] f32   : logsumexp per k-row
// x_t  [B][4096][160]  : attn residual out, c-fastest; cols 130-159 = poison,
//                        neutralized by zero-padded W1b columns.
// x1_t [B][4096][256]  : conv1 out
// W1b  [256][160], W2b [128][256] : prep-converted bf16 weights
// ---------------------------------------------------------------------------

typedef __attribute__((ext_vector_type(8))) short   bf16x8;
typedef __attribute__((ext_vector_type(4))) float   f32x4;
typedef __attribute__((ext_vector_type(8))) unsigned short u16x8;
typedef __attribute__((ext_vector_type(4))) unsigned short u16x4;

static __device__ __forceinline__ unsigned short f2bf(float f) {
    union { float f; unsigned u; } v; v.f = f;
    unsigned r = v.u + 0x7FFFu + ((v.u >> 16) & 1u);   // RNE, finite inputs
    return (unsigned short)(r >> 16);
}

#define MFMA16(a, b, c) __builtin_amdgcn_mfma_f32_16x16x32_bf16((a), (b), (c), 0, 0, 0)

// ---------------------------------------------------------------------------
// K0: weight prep — W1 [256][130] f32 -> W1b [256][160] bf16 (zero pad),
//     W2 [128][256] f32 -> W2b bf16.
// ---------------------------------------------------------------------------
__global__ __launch_bounds__(256) void prep_kernel(
    const float* __restrict__ W1, const float* __restrict__ W2,
    unsigned short* __restrict__ W1b, unsigned short* __restrict__ W2b)
{
    int i = blockIdx.x * 256 + threadIdx.x;
    if (i < 256 * CIN_P) {
        int o = i / CIN_P, c = i - o * CIN_P;
        W1b[i] = (c < CIN) ? f2bf(W1[o * CIN + c]) : (unsigned short)0;
    } else {
        int j = i - 256 * CIN_P;           // < 128*256 by grid sizing
        W2b[j] = f2bf(W2[j]);
    }
}

// ---------------------------------------------------------------------------
// K1: fgh projections (scalar f32 compute), writes f_t/g_t transposed bf16 +
//     h row-major bf16.
// ---------------------------------------------------------------------------
__global__ __launch_bounds__(256) void fgh_kernel(
    const float* __restrict__ inp,
    const float* __restrict__ WF, const float* __restrict__ bF,
    const float* __restrict__ WG, const float* __restrict__ bG,
    const float* __restrict__ WH, const float* __restrict__ bH,
    unsigned short* __restrict__ f_t, unsigned short* __restrict__ g_t,
    unsigned short* __restrict__ h)
{
    const int b  = blockIdx.z;
    const int og = blockIdx.y;
    const int m  = blockIdx.x * 256 + threadIdx.x;

    __shared__ float wl[8][CIN];
    __shared__ float bl[8];

    for (int idx = threadIdx.x; idx < 8 * CIN; idx += 256) {
        int i = idx / CIN, c = idx - i * CIN;
        int o = og * 8 + i;
        float w = 0.f;
        if (o < 32)         w = WF[o * CIN + c];
        else if (o < 64)    w = WG[(o - 32) * CIN + c];
        else if (o < NROWS) w = WH[(o - 64) * CIN + c];
        wl[i][c] = w;
    }
    if (threadIdx.x < 8) {
        int o = og * 8 + threadIdx.x;
        float bv = 0.f;
        if (o < 32)         bv = bF[o];
        else if (o < 64)    bv = bG[o - 32];
        else if (o < NROWS) bv = bH[o - 64];
        bl[threadIdx.x] = bv;
    }
    __syncthreads();

    float acc[8];
    #pragma unroll
    for (int i = 0; i < 8; ++i) acc[i] = bl[i];

    const int mn = m & (NN - 1);
    #pragma unroll 4
    for (int c = 0; c < CC; ++c) {
        float v = inp[((size_t)b * CC + c) * NN + mn];
        #pragma unroll
        for (int i = 0; i < 8; ++i) acc[i] += wl[i][c] * v;
    }
    const int q = m >> 10;
    const float gx = (q >> 1) ? 0.2f : -0.2f;
    const float gy = (q & 1)  ? 0.2f : -0.2f;
    #pragma unroll
    for (int i = 0; i < 8; ++i) acc[i] += wl[i][CC] * gx + wl[i][CC + 1] * gy;

    if (og < 4) {                       // f rows 0-31 -> f_t[m][og*8..+8]
        u16x8 pk;
        #pragma unroll
        for (int i = 0; i < 8; ++i) pk[i] = f2bf(fmaxf(acc[i], 0.f));
        *(u16x8*)&f_t[((size_t)b * MM + m) * 32 + og * 8] = pk;
    } else if (og < 8) {                // g rows 0-31 -> g_t
        u16x8 pk;
        #pragma unroll
        for (int i = 0; i < 8; ++i) pk[i] = f2bf(fmaxf(acc[i], 0.f));
        *(u16x8*)&g_t[((size_t)b * MM + m) * 32 + (og - 4) * 8] = pk;
    } else {                            // h rows (o-64), row-major
        #pragma unroll
        for (int i = 0; i < 8; ++i) {
            int o = og * 8 + i;
            if (o < NROWS)
                h[((size_t)b * CIN + (o - 64)) * MM + m] = f2bf(fmaxf(acc[i], 0.f));
        }
    }
}

// ---------------------------------------------------------------------------
// K2: pass A via MFMA. Block = 64 k-rows (wave w -> k-tile w), streams m.
// L[k] = 4 + log(sum_m exp(s[k,m]-4)).   No LDS at all.
// ---------------------------------------------------------------------------
__global__ __launch_bounds__(256) void rowstats_kernel(
    const unsigned short* __restrict__ f_t, const unsigned short* __restrict__ g_t,
    float* __restrict__ L)
{
    const int b  = blockIdx.y;
    const int k0 = blockIdx.x * 64;
    const int lane = threadIdx.x & 63, w = threadIdx.x >> 6;
    const int l15 = lane & 15, lg = lane >> 4;

    const bf16x8 aG = *(const bf16x8*)&g_t[((size_t)b * MM + k0 + w * 16 + l15) * 32 + lg * 8];
    const f32x4 zero = {0.f, 0.f, 0.f, 0.f};
    f32x4 sum = zero;

    for (int mc = 0; mc < MM; mc += 64) {
        #pragma unroll
        for (int mt = 0; mt < 4; ++mt) {
            bf16x8 fB = *(const bf16x8*)&f_t[((size_t)b * MM + mc + mt * 16 + l15) * 32 + lg * 8];
            f32x4 s = MFMA16(aG, fB, zero);
            #pragma unroll
            for (int r = 0; r < 4; ++r) sum[r] += __expf(s[r] - 4.0f);
        }
    }

    #pragma unroll
    for (int d = 1; d < 16; d <<= 1) {
        #pragma unroll
        for (int r = 0; r < 4; ++r) sum[r] += __shfl_xor(sum[r], d);
    }
    if (l15 == 0) {
        #pragma unroll
        for (int r = 0; r < 4; ++r)
            L[b * MM + k0 + w * 16 + lg * 4 + r] = 4.0f + __logf(sum[r]);
    }
}

// ---------------------------------------------------------------------------
// K3: pass B via MFMA. Block = 64 m-cols (wave w -> m-tile w in phase 2,
// k-tile w in phase 1), streams k in chunks of 64.
// ---------------------------------------------------------------------------
__global__ __launch_bounds__(256) void attn_kernel(
    const unsigned short* __restrict__ f_t, const unsigned short* __restrict__ g_t,
    const unsigned short* __restrict__ h,   const float* __restrict__ L,
    const float* __restrict__ inp,          const float* __restrict__ gamma_p,
    unsigned short* __restrict__ x_t)
{
    const int b  = blockIdx.y;
    const int m0 = blockIdx.x * 64;
    const int tid = threadIdx.x;
    const int lane = tid & 63, w = tid >> 6;
    const int l15 = lane & 15, lg = lane >> 4;

    __shared__ unsigned short Hs[144 * MPAD];   // [c][k] padded, 23.0 KB
    __shared__ unsigned short Et[64 * MPAD];    // [m][k] padded, 10.2 KB

    const f32x4 zero = {0.f, 0.f, 0.f, 0.f};

    // F B-frags for phase 1 (fixed per block): mtile mt, rows m0+mt*16+l15
    bf16x8 fF[4];
    #pragma unroll
    for (int mt = 0; mt < 4; ++mt)
        fF[mt] = *(const bf16x8*)&f_t[((size_t)b * MM + m0 + mt * 16 + l15) * 32 + lg * 8];

    f32x4 acc[9];
    #pragma unroll
    for (int ct = 0; ct < 9; ++ct) acc[ct] = zero;

    const float gam = gamma_p[0];

    for (int kc = 0; kc < MM; kc += 64) {
        // --- issue H-chunk staging loads (global -> regs) ------------------
        bf16x8 hst[5];
        #pragma unroll
        for (int u = 0; u < 5; ++u) {
            int idx = tid + u * 256;            // 1152 units of 8 bf16
            int c = idx >> 3, seg = idx & 7;
            bf16x8 v = {0,0,0,0,0,0,0,0};
            if (idx < 1152 && c < CIN)
                v = *(const bf16x8*)&h[((size_t)b * CIN + c) * MM + kc + seg * 8];
            hst[u] = v;
        }

        // --- phase 1: S-tiles for this wave's k-tile (k = kc + w*16 + ...) -
        bf16x8 aG = *(const bf16x8*)&g_t[((size_t)b * MM + kc + w * 16 + l15) * 32 + lg * 8];
        float Lr[4];
        #pragma unroll
        for (int r = 0; r < 4; ++r)
            Lr[r] = L[b * MM + kc + w * 16 + lg * 4 + r];

        f32x4 s[4];
        #pragma unroll
        for (int mt = 0; mt < 4; ++mt)
            s[mt] = MFMA16(aG, fF[mt], zero);

        __syncthreads();   // prev chunk's Et/Hs fully consumed

        // E = exp(s - L), write transposed [m][k] (4 consecutive k per lane)
        #pragma unroll
        for (int mt = 0; mt < 4; ++mt) {
            u16x4 pk;
            #pragma unroll
            for (int r = 0; r < 4; ++r) pk[r] = f2bf(__expf(s[mt][r] - Lr[r]));
            *(u16x4*)&Et[(size_t)(mt * 16 + l15) * MPAD + w * 16 + lg * 4] = pk;
        }
        // H staging regs -> LDS
        #pragma unroll
        for (int u = 0; u < 5; ++u) {
            int idx = tid + u * 256;
            int c = idx >> 3, seg = idx & 7;
            if (idx < 1152)
                *(bf16x8*)&Hs[(size_t)c * MPAD + seg * 8] = hst[u];
        }
        __syncthreads();

        // --- phase 2: O-accumulate, wave's m-tile = w ----------------------
        bf16x8 eB[2];
        #pragma unroll
        for (int ks = 0; ks < 2; ++ks)
            eB[ks] = *(const bf16x8*)&Et[(size_t)(w * 16 + l15) * MPAD + ks * 32 + lg * 8];
        #pragma unroll
        for (int ct = 0; ct < 9; ++ct) {
            #pragma unroll
            for (int ks = 0; ks < 2; ++ks) {
                bf16x8 aH = *(const bf16x8*)&Hs[(size_t)(ct * 16 + l15) * MPAD + ks * 32 + lg * 8];
                acc[ct] = MFMA16(aH, eB[ks], acc[ct]);
            }
        }
    }

    // --- epilogue: x_t[m][c] = gamma*O + net ------------------------------
    const int m = m0 + w * 16 + l15;
    const int mn = m & (NN - 1);
    const int q = m >> 10;
    const float gx = (q >> 1) ? 0.2f : -0.2f;
    const float gy = (q & 1)  ? 0.2f : -0.2f;

    #pragma unroll
    for (int ct = 0; ct < 9; ++ct) {
        const int cbase = ct * 16 + lg * 4;
        if (cbase < CC) {
            u16x4 pk;
            #pragma unroll
            for (int r = 0; r < 4; ++r) {
                float net = inp[((size_t)b * CC + cbase + r) * NN + mn];
                pk[r] = f2bf(gam * acc[ct][r] + net);
            }
            *(u16x4*)&x_t[((size_t)b * MM + m) * CIN_P + cbase] = pk;
        } else if (cbase == CC) {  // c = 128, 129 (grid channels)
            x_t[((size_t)b * MM + m) * CIN_P + CC]     = f2bf(gam * acc[ct][0] + gx);
            x_t[((size_t)b * MM + m) * CIN_P + CC + 1] = f2bf(gam * acc[ct][1] + gy);
        }
    }
}

// ---------------------------------------------------------------------------
// K4/K5: conv1x1 + relu via MFMA. Block = 64 m (wave w -> m-tile w), no LDS.
// KS = K-slices of 32, OT = output 16-tiles.
// ---------------------------------------------------------------------------
template <int KS, int OT, bool OUTF32>
__global__ __launch_bounds__(256) void conv_mfma_kernel(
    const unsigned short* __restrict__ Wb, const float* __restrict__ bias,
    const unsigned short* __restrict__ in_t,
    unsigned short* __restrict__ out_bf, float* __restrict__ out_f32)
{
    const int CINP = KS * 32;
    const int lane = threadIdx.x & 63, w = threadIdx.x >> 6;
    const int l15 = lane & 15, lg = lane >> 4;
    const int m = blockIdx.x * 64 + w * 16 + l15;   // global m in [0, B*MM)

    bf16x8 bF[KS];
    #pragma unroll
    for (int ks = 0; ks < KS; ++ks)
        bF[ks] = *(const bf16x8*)&in_t[(size_t)m * CINP + ks * 32 + lg * 8];

    const f32x4 zero = {0.f, 0.f, 0.f, 0.f};

    #pragma unroll
    for (int ot = 0; ot < OT; ++ot) {
        f32x4 acc = zero;
        #pragma unroll
        for (int ks = 0; ks < KS; ++ks) {
            bf16x8 aW = *(const bf16x8*)&Wb[(size_t)(ot * 16 + l15) * CINP + ks * 32 + lg * 8];
            acc = MFMA16(aW, bF[ks], acc);
        }
        const int obase = ot * 16 + lg * 4;
        if (OUTF32) {
            const int bb = m >> 12, mm = m & (MM - 1);
            #pragma unroll
            for (int r = 0; r < 4; ++r)
                out_f32[((size_t)bb * (OT * 16) + obase + r) * MM + mm] =
                    fmaxf(acc[r] + bias[obase + r], 0.f);
        } else {
            u16x4 pk;
            #pragma unroll
            for (int r = 0; r < 4; ++r)
                pk[r] = f2bf(fmaxf(acc[r] + bias[obase + r], 0.f));
            *(u16x4*)&out_bf[(size_t)m * (OT * 16) + obase] = pk;
        }
    }
}

// ---------------------------------------------------------------------------
extern "C" void kernel_launch(void* const* d_in, const int* in_sizes, int n_in,
                              void* d_out, int out_size, void* d_ws, size_t ws_size,
                              hipStream_t stream)
{
    const float* inp   = (const float*)d_in[0];
    const float* WF    = (const float*)d_in[1];
    const float* bF    = (const float*)d_in[2];
    const float* WG    = (const float*)d_in[3];
    const float* bG    = (const float*)d_in[4];
    const float* WH    = (const float*)d_in[5];
    const float* bH    = (const float*)d_in[6];
    const float* gamma = (const float*)d_in[7];
    const float* W1    = (const float*)d_in[8];
    const float* b1    = (const float*)d_in[9];
    const float* W2    = (const float*)d_in[10];
    const float* b2    = (const float*)d_in[11];
    float* out = (float*)d_out;

    char* p = (char*)d_ws;
    auto alloc = [&](size_t bytes) { char* q = p; p += (bytes + 255) & ~(size_t)255; return q; };
    unsigned short* f_t  = (unsigned short*)alloc((size_t)BB * MM * 32 * 2);
    unsigned short* g_t  = (unsigned short*)alloc((size_t)BB * MM * 32 * 2);
    unsigned short* h    = (unsigned short*)alloc((size_t)BB * CIN * MM * 2);
    float*          L    = (float*)alloc((size_t)BB * MM * 4);
    unsigned short* x_t  = (unsigned short*)alloc((size_t)BB * MM * CIN_P * 2);
    unsigned short* x1_t = (unsigned short*)alloc((size_t)BB * MM * 256 * 2);
    unsigned short* W1b  = (unsigned short*)alloc((size_t)256 * CIN_P * 2);
    unsigned short* W2b  = (unsigned short*)alloc((size_t)128 * 256 * 2);

    prep_kernel<<<288, 256, 0, stream>>>(W1, W2, W1b, W2b);

    fgh_kernel<<<dim3(MM / 256, 25, BB), 256, 0, stream>>>(
        inp, WF, bF, WG, bG, WH, bH, f_t, g_t, h);

    rowstats_kernel<<<dim3(MM / 64, BB), 256, 0, stream>>>(f_t, g_t, L);

    attn_kernel<<<dim3(MM / 64, BB), 256, 0, stream>>>(
        f_t, g_t, h, L, inp, gamma, x_t);

    conv_mfma_kernel<5, 16, false><<<dim3(BB * MM / 64), 256, 0, stream>>>(
        W1b, b1, x_t, x1_t, nullptr);

    conv_mfma_kernel<8, 8, true><<<dim3(BB * MM / 64), 256, 0, stream>>>(
        W2b, b2, x1_t, nullptr, out);
}

// Round 5
// 298.267 us; speedup vs baseline: 8.6683x; 1.0291x over previous
//
#include <hip/hip_runtime.h>
#include <hip/hip_bf16.h>
#include <math.h>

// Problem constants (B=8, C=128, N=1024, UP=4)
#define BB    8
#define CC    128
#define NN    1024
#define MM    4096     // UP*N
#define CIN   130      // C+2
#define NROWS 194      // 32 f + 32 g + 130 h
#define MPAD  72       // LDS row pad: 36 words -> bank stride 4 -> minimal 2x tiling
#define CIN_P 160      // padded channel count (130 -> 160 = 5 K-slices of 32)
#define OPAD  208      // padded fgh output rows (13 tiles of 16)

// ---- Layouts (bf16 unless noted) ------------------------------------------
// net_t [B*M][160] : transposed+padded input (c-fastest), grid cols fused
// f_t   [B*M][32]  : f transposed   g_t [B*M][32] : g transposed
// h     [B][130][M]: row-major
// Lsum  [B][M] f32 : sum_m exp(s[k,m]-4)   (atomic-accumulated)
// P     [2][B][130][M] f32 : k-split partial O
// x_t   [B*M][160] : attn+residual (pad cols zeroed)
// x1_t  [B*M][256] : conv1 out (ALIASES P — P dead after combine)
// Wfgh  [208][160], W1b [256][160], W2b [128][256], bfgh f32[208]
// ---------------------------------------------------------------------------

typedef __attribute__((ext_vector_type(8))) short   bf16x8;
typedef __attribute__((ext_vector_type(4))) float   f32x4;
typedef __attribute__((ext_vector_type(8))) unsigned short u16x8;
typedef __attribute__((ext_vector_type(4))) unsigned short u16x4;

static __device__ __forceinline__ unsigned short f2bf(float f) {
    union { float f; unsigned u; } v; v.f = f;
    unsigned r = v.u + 0x7FFFu + ((v.u >> 16) & 1u);   // RNE, finite inputs
    return (unsigned short)(r >> 16);
}
static __device__ __forceinline__ float bf2f(unsigned short s) {
    union { unsigned u; float f; } v; v.u = ((unsigned)s) << 16;
    return v.f;
}

#define MFMA16(a, b, c) __builtin_amdgcn_mfma_f32_16x16x32_bf16((a), (b), (c), 0, 0, 0)

// ---------------------------------------------------------------------------
// K0: prep — pack/pad all weights to bf16, zero Lsum.
// Regions: [0,40960) W1b | [..,73728) W2b | [..,107008) Wfgh | [..,107216) bfgh
//          | [..,139984) Lsum zero
// ---------------------------------------------------------------------------
__global__ __launch_bounds__(256) void prep_kernel(
    const float* __restrict__ W1, const float* __restrict__ W2,
    const float* __restrict__ WF, const float* __restrict__ WG,
    const float* __restrict__ WH, const float* __restrict__ bFp,
    const float* __restrict__ bGp, const float* __restrict__ bHp,
    unsigned short* __restrict__ W1b, unsigned short* __restrict__ W2b,
    unsigned short* __restrict__ Wfgh, float* __restrict__ bfgh,
    float* __restrict__ Lsum)
{
    int i = blockIdx.x * 256 + threadIdx.x;
    if (i < 40960) {
        int o = i / CIN_P, c = i - o * CIN_P;
        W1b[i] = (c < CIN) ? f2bf(W1[o * CIN + c]) : (unsigned short)0;
    } else if (i < 73728) {
        int j = i - 40960;
        W2b[j] = f2bf(W2[j]);
    } else if (i < 107008) {
        int j = i - 73728;
        int o = j / CIN_P, c = j - o * CIN_P;
        float w = 0.f;
        if (c < CIN) {
            if (o < 32)         w = WF[o * CIN + c];
            else if (o < 64)    w = WG[(o - 32) * CIN + c];
            else if (o < NROWS) w = WH[(o - 64) * CIN + c];
        }
        Wfgh[j] = f2bf(w);
    } else if (i < 107216) {
        int o = i - 107008;
        float bv = 0.f;
        if (o < 32)         bv = bFp[o];
        else if (o < 64)    bv = bGp[o - 32];
        else if (o < NROWS) bv = bHp[o - 64];
        bfgh[o] = bv;
    } else if (i < 139984) {
        Lsum[i - 107216] = 0.f;
    }
}

// ---------------------------------------------------------------------------
// K1: transpose — inp [B][128][1024] f32 -> net_t [B*M][160] bf16
// (4 grid-repeats per n, grid channels 128/129, zeros 130-159)
// ---------------------------------------------------------------------------
__global__ __launch_bounds__(256) void transpose_kernel(
    const float* __restrict__ inp, unsigned short* __restrict__ net_t)
{
    const int b  = blockIdx.y;
    const int n0 = blockIdx.x * 32;
    const int t  = threadIdx.x;

    __shared__ float tile[CC][33];

    for (int idx = t; idx < CC * 32; idx += 256) {
        int c = idx >> 5, n = idx & 31;
        tile[c][n] = inp[((size_t)b * CC + c) * NN + n0 + n];
    }
    __syncthreads();

    const int n = t >> 3, grp = t & 7;
    #pragma unroll
    for (int q = 0; q < 4; ++q) {
        const int m = q * NN + n0 + n;
        const float gx = (q >> 1) ? 0.2f : -0.2f;
        const float gy = (q & 1)  ? 0.2f : -0.2f;
        for (int j = grp; j < 20; j += 8) {
            const int c0 = j * 8;
            u16x8 pk;
            #pragma unroll
            for (int i = 0; i < 8; ++i) {
                int c = c0 + i;
                float v = (c < CC) ? tile[c][n]
                        : (c == CC) ? gx : (c == CC + 1) ? gy : 0.f;
                pk[i] = f2bf(v);
            }
            *(u16x8*)&net_t[((size_t)b * MM + m) * CIN_P + c0] = pk;
        }
    }
}

// ---------------------------------------------------------------------------
// K2: proj — fgh = relu(Wfgh @ net + b) via MFMA. No LDS, no barriers.
// Wave = 16-m tile; 13 output tiles x 5 K-slices = 65 MFMAs.
// ---------------------------------------------------------------------------
__global__ __launch_bounds__(256) void proj_kernel(
    const unsigned short* __restrict__ Wfgh, const float* __restrict__ bfgh,
    const unsigned short* __restrict__ net_t,
    unsigned short* __restrict__ f_t, unsigned short* __restrict__ g_t,
    unsigned short* __restrict__ h)
{
    const int lane = threadIdx.x & 63, w = threadIdx.x >> 6;
    const int l15 = lane & 15, lg = lane >> 4;
    const int mg = blockIdx.x * 64 + w * 16 + l15;   // over B*M
    const int b = mg >> 12, m = mg & (MM - 1);

    bf16x8 nf[5];
    #pragma unroll
    for (int ks = 0; ks < 5; ++ks)
        nf[ks] = *(const bf16x8*)&net_t[(size_t)mg * CIN_P + ks * 32 + lg * 8];

    const f32x4 zero = {0.f, 0.f, 0.f, 0.f};

    #pragma unroll
    for (int ot = 0; ot < 13; ++ot) {
        f32x4 acc = zero;
        #pragma unroll
        for (int ks = 0; ks < 5; ++ks) {
            bf16x8 aW = *(const bf16x8*)&Wfgh[(size_t)(ot * 16 + l15) * CIN_P + ks * 32 + lg * 8];
            acc = MFMA16(aW, nf[ks], acc);
        }
        const int o0 = ot * 16 + lg * 4;
        float v[4];
        #pragma unroll
        for (int r = 0; r < 4; ++r) v[r] = fmaxf(acc[r] + bfgh[o0 + r], 0.f);

        if (ot < 2) {
            u16x4 pk;
            #pragma unroll
            for (int r = 0; r < 4; ++r) pk[r] = f2bf(v[r]);
            *(u16x4*)&f_t[(size_t)mg * 32 + o0] = pk;
        } else if (ot < 4) {
            u16x4 pk;
            #pragma unroll
            for (int r = 0; r < 4; ++r) pk[r] = f2bf(v[r]);
            *(u16x4*)&g_t[(size_t)mg * 32 + (o0 - 32)] = pk;
        } else {
            #pragma unroll
            for (int r = 0; r < 4; ++r) {
                int o = o0 + r;
                if (o < NROWS)
                    h[((size_t)b * CIN + (o - 64)) * MM + m] = f2bf(v[r]);
            }
        }
    }
}

// ---------------------------------------------------------------------------
// K3: rowstats — Lsum[k] += sum_{m in split} exp(s[k,m]-4), m-split=4, atomic.
// ---------------------------------------------------------------------------
__global__ __launch_bounds__(256) void rowstats_kernel(
    const unsigned short* __restrict__ f_t, const unsigned short* __restrict__ g_t,
    float* __restrict__ Lsum)
{
    const int b  = blockIdx.y;
    const int k0 = blockIdx.x * 64;
    const int m0 = blockIdx.z * 1024;
    const int lane = threadIdx.x & 63, w = threadIdx.x >> 6;
    const int l15 = lane & 15, lg = lane >> 4;

    const bf16x8 aG = *(const bf16x8*)&g_t[((size_t)b * MM + k0 + w * 16 + l15) * 32 + lg * 8];
    const f32x4 zero = {0.f, 0.f, 0.f, 0.f};
    f32x4 sum = zero;

    for (int mc = m0; mc < m0 + 1024; mc += 64) {
        #pragma unroll
        for (int mt = 0; mt < 4; ++mt) {
            bf16x8 fB = *(const bf16x8*)&f_t[((size_t)b * MM + mc + mt * 16 + l15) * 32 + lg * 8];
            f32x4 s = MFMA16(aG, fB, zero);
            #pragma unroll
            for (int r = 0; r < 4; ++r) sum[r] += __expf(s[r] - 4.0f);
        }
    }

    #pragma unroll
    for (int d = 1; d < 16; d <<= 1) {
        #pragma unroll
        for (int r = 0; r < 4; ++r) sum[r] += __shfl_xor(sum[r], d);
    }
    if (l15 == 0) {
        #pragma unroll
        for (int r = 0; r < 4; ++r)
            atomicAdd(&Lsum[b * MM + k0 + w * 16 + lg * 4 + r], sum[r]);
    }
}

// ---------------------------------------------------------------------------
// K4: attn — k-split=2, partial O to P (f32). MPAD=72 (minimal bank tiling).
// ---------------------------------------------------------------------------
__global__ __launch_bounds__(256) void attn_kernel(
    const unsigned short* __restrict__ f_t, const unsigned short* __restrict__ g_t,
    const unsigned short* __restrict__ h,   const float* __restrict__ Lsum,
    float* __restrict__ P)
{
    const int b  = blockIdx.y;
    const int m0 = blockIdx.x * 64;
    const int kz = blockIdx.z;
    const int tid = threadIdx.x;
    const int lane = tid & 63, w = tid >> 6;
    const int l15 = lane & 15, lg = lane >> 4;

    __shared__ unsigned short Hs[144 * MPAD];   // 20.7 KB
    __shared__ unsigned short Et[64 * MPAD];    //  9.2 KB

    const f32x4 zero = {0.f, 0.f, 0.f, 0.f};

    bf16x8 fF[4];
    #pragma unroll
    for (int mt = 0; mt < 4; ++mt)
        fF[mt] = *(const bf16x8*)&f_t[((size_t)b * MM + m0 + mt * 16 + l15) * 32 + lg * 8];

    f32x4 acc[9];
    #pragma unroll
    for (int ct = 0; ct < 9; ++ct) acc[ct] = zero;

    const int kbeg = kz * (MM / 2), kend = kbeg + (MM / 2);
    for (int kc = kbeg; kc < kend; kc += 64) {
        // stage H chunk to regs
        bf16x8 hst[5];
        #pragma unroll
        for (int u = 0; u < 5; ++u) {
            int idx = tid + u * 256;
            int c = idx >> 3, seg = idx & 7;
            bf16x8 v = {0,0,0,0,0,0,0,0};
            if (idx < 1152 && c < CIN)
                v = *(const bf16x8*)&h[((size_t)b * CIN + c) * MM + kc + seg * 8];
            hst[u] = v;
        }

        // phase 1: S for this wave's k-tile
        bf16x8 aG = *(const bf16x8*)&g_t[((size_t)b * MM + kc + w * 16 + l15) * 32 + lg * 8];
        float rinv[4];
        #pragma unroll
        for (int r = 0; r < 4; ++r)
            rinv[r] = 1.0f / Lsum[b * MM + kc + w * 16 + lg * 4 + r];

        f32x4 s[4];
        #pragma unroll
        for (int mt = 0; mt < 4; ++mt)
            s[mt] = MFMA16(aG, fF[mt], zero);

        __syncthreads();   // prev Et/Hs consumed

        #pragma unroll
        for (int mt = 0; mt < 4; ++mt) {
            u16x4 pk;
            #pragma unroll
            for (int r = 0; r < 4; ++r)
                pk[r] = f2bf(__expf(s[mt][r] - 4.0f) * rinv[r]);
            *(u16x4*)&Et[(size_t)(mt * 16 + l15) * MPAD + w * 16 + lg * 4] = pk;
        }
        #pragma unroll
        for (int u = 0; u < 5; ++u) {
            int idx = tid + u * 256;
            int c = idx >> 3, seg = idx & 7;
            if (idx < 1152)
                *(bf16x8*)&Hs[(size_t)c * MPAD + seg * 8] = hst[u];
        }
        __syncthreads();

        // phase 2: O accumulate
        bf16x8 eB[2];
        #pragma unroll
        for (int ks = 0; ks < 2; ++ks)
            eB[ks] = *(const bf16x8*)&Et[(size_t)(w * 16 + l15) * MPAD + ks * 32 + lg * 8];
        #pragma unroll
        for (int ct = 0; ct < 9; ++ct) {
            #pragma unroll
            for (int ks = 0; ks < 2; ++ks) {
                bf16x8 aH = *(const bf16x8*)&Hs[(size_t)(ct * 16 + l15) * MPAD + ks * 32 + lg * 8];
                acc[ct] = MFMA16(aH, eB[ks], acc[ct]);
            }
        }
    }

    // partial store: P[kz][b][c][m], rows c<130
    const int m = m0 + w * 16 + l15;
    #pragma unroll
    for (int ct = 0; ct < 9; ++ct) {
        #pragma unroll
        for (int r = 0; r < 4; ++r) {
            const int c = ct * 16 + lg * 4 + r;
            if (c < CIN)
                P[((size_t)(kz * BB + b) * CIN + c) * MM + m] = acc[ct][r];
        }
    }
}

// ---------------------------------------------------------------------------
// K5: combine — x_t = gamma*(P0+P1) + net_t (pad cols -> 0)
// ---------------------------------------------------------------------------
__global__ __launch_bounds__(256) void combine_kernel(
    const float* __restrict__ P, const unsigned short* __restrict__ net_t,
    const float* __restrict__ gamma_p, unsigned short* __restrict__ x_t)
{
    const int b = blockIdx.y;
    const int moff = threadIdx.x & 63, cg = threadIdx.x >> 6;
    const int m = blockIdx.x * 64 + moff;
    const float gam = gamma_p[0];

    #pragma unroll
    for (int j = 0; j < 5; ++j) {
        const int c0 = cg * 40 + j * 8;
        u16x8 net8 = *(const u16x8*)&net_t[((size_t)b * MM + m) * CIN_P + c0];
        u16x8 pk;
        #pragma unroll
        for (int i = 0; i < 8; ++i) {
            const int c = c0 + i;
            if (c < CIN) {
                float p0 = P[((size_t)(0 * BB + b) * CIN + c) * MM + m];
                float p1 = P[((size_t)(1 * BB + b) * CIN + c) * MM + m];
                pk[i] = f2bf(gam * (p0 + p1) + bf2f(net8[i]));
            } else {
                pk[i] = 0;
            }
        }
        *(u16x8*)&x_t[((size_t)b * MM + m) * CIN_P + c0] = pk;
    }
}

// ---------------------------------------------------------------------------
// K6/K7: conv1x1 + relu via MFMA (unchanged from round 2)
// ---------------------------------------------------------------------------
template <int KS, int OT, bool OUTF32>
__global__ __launch_bounds__(256) void conv_mfma_kernel(
    const unsigned short* __restrict__ Wb, const float* __restrict__ bias,
    const unsigned short* __restrict__ in_t,
    unsigned short* __restrict__ out_bf, float* __restrict__ out_f32)
{
    const int CINP = KS * 32;
    const int lane = threadIdx.x & 63, w = threadIdx.x >> 6;
    const int l15 = lane & 15, lg = lane >> 4;
    const int m = blockIdx.x * 64 + w * 16 + l15;   // over B*M

    bf16x8 bFr[KS];
    #pragma unroll
    for (int ks = 0; ks < KS; ++ks)
        bFr[ks] = *(const bf16x8*)&in_t[(size_t)m * CINP + ks * 32 + lg * 8];

    const f32x4 zero = {0.f, 0.f, 0.f, 0.f};

    #pragma unroll
    for (int ot = 0; ot < OT; ++ot) {
        f32x4 acc = zero;
        #pragma unroll
        for (int ks = 0; ks < KS; ++ks) {
            bf16x8 aW = *(const bf16x8*)&Wb[(size_t)(ot * 16 + l15) * CINP + ks * 32 + lg * 8];
            acc = MFMA16(aW, bFr[ks], acc);
        }
        const int obase = ot * 16 + lg * 4;
        if (OUTF32) {
            const int bb = m >> 12, mm = m & (MM - 1);
            #pragma unroll
            for (int r = 0; r < 4; ++r)
                out_f32[((size_t)bb * (OT * 16) + obase + r) * MM + mm] =
                    fmaxf(acc[r] + bias[obase + r], 0.f);
        } else {
            u16x4 pk;
            #pragma unroll
            for (int r = 0; r < 4; ++r)
                pk[r] = f2bf(fmaxf(acc[r] + bias[obase + r], 0.f));
            *(u16x4*)&out_bf[(size_t)m * (OT * 16) + obase] = pk;
        }
    }
}

// ---------------------------------------------------------------------------
extern "C" void kernel_launch(void* const* d_in, const int* in_sizes, int n_in,
                              void* d_out, int out_size, void* d_ws, size_t ws_size,
                              hipStream_t stream)
{
    const float* inp   = (const float*)d_in[0];
    const float* WF    = (const float*)d_in[1];
    const float* bF    = (const float*)d_in[2];
    const float* WG    = (const float*)d_in[3];
    const float* bG    = (const float*)d_in[4];
    const float* WH    = (const float*)d_in[5];
    const float* bH    = (const float*)d_in[6];
    const float* gamma = (const float*)d_in[7];
    const float* W1    = (const float*)d_in[8];
    const float* b1    = (const float*)d_in[9];
    const float* W2    = (const float*)d_in[10];
    const float* b2    = (const float*)d_in[11];
    float* out = (float*)d_out;

    char* p = (char*)d_ws;
    auto alloc = [&](size_t bytes) { char* q = p; p += (bytes + 255) & ~(size_t)255; return q; };
    unsigned short* net_t = (unsigned short*)alloc((size_t)BB * MM * CIN_P * 2);  // 10.5 MB
    unsigned short* f_t   = (unsigned short*)alloc((size_t)BB * MM * 32 * 2);     //  2.1 MB
    unsigned short* g_t   = (unsigned short*)alloc((size_t)BB * MM * 32 * 2);     //  2.1 MB
    unsigned short* h     = (unsigned short*)alloc((size_t)BB * CIN * MM * 2);    //  8.5 MB
    float*          Lsum  = (float*)alloc((size_t)BB * MM * 4);                   //  0.13 MB
    unsigned short* x_t   = (unsigned short*)alloc((size_t)BB * MM * CIN_P * 2);  // 10.5 MB
    float*          P     = (float*)alloc((size_t)2 * BB * CIN * MM * 4);         // 34.1 MB
    unsigned short* x1_t  = (unsigned short*)P;   // alias: P dead after combine
    unsigned short* W1b   = (unsigned short*)alloc((size_t)256 * CIN_P * 2);
    unsigned short* W2b   = (unsigned short*)alloc((size_t)128 * 256 * 2);
    unsigned short* Wfgh  = (unsigned short*)alloc((size_t)OPAD * CIN_P * 2);
    float*          bfgh  = (float*)alloc((size_t)OPAD * 4);

    prep_kernel<<<547, 256, 0, stream>>>(W1, W2, WF, WG, WH, bF, bG, bH,
                                         W1b, W2b, Wfgh, bfgh, Lsum);

    transpose_kernel<<<dim3(NN / 32, BB), 256, 0, stream>>>(inp, net_t);

    proj_kernel<<<dim3(BB * MM / 64), 256, 0, stream>>>(
        Wfgh, bfgh, net_t, f_t, g_t, h);

    rowstats_kernel<<<dim3(MM / 64, BB, 4), 256, 0, stream>>>(f_t, g_t, Lsum);

    attn_kernel<<<dim3(MM / 64, BB, 2), 256, 0, stream>>>(f_t, g_t, h, Lsum, P);

    combine_kernel<<<dim3(MM / 64, BB), 256, 0, stream>>>(P, net_t, gamma, x_t);

    conv_mfma_kernel<5, 16, false><<<dim3(BB * MM / 64), 256, 0, stream>>>(
        W1b, b1, x_t, x1_t, nullptr);

    conv_mfma_kernel<8, 8, true><<<dim3(BB * MM / 64), 256, 0, stream>>>(
        W2b, b2, x1_t, nullptr, out);
}